// Round 3
// baseline (371.987 us; speedup 1.0000x reference)
//
#include <hip/hip_runtime.h>
#include <hip/hip_bf16.h>

#define B_    8
#define CIN   64
#define COUT  64
#define RN_   4
#define H_    128
#define W_    128
#define HW_   (H_ * W_)
#define BN_EPS 1e-5f

typedef short v8s __attribute__((ext_vector_type(8)));
typedef float v4f __attribute__((ext_vector_type(4)));

__device__ __forceinline__ unsigned short f2bf(float f) {
    unsigned int u = __float_as_uint(f);
    u += 0x7FFFu + ((u >> 16) & 1u);       // round-to-nearest-even
    return (unsigned short)(u >> 16);
}

// ---------------------------------------------------------------------------
// x fp32 [b][c][h][w] -> xT bf16 [b][h][w][c]   (channel-innermost for b128 LDS)
// ---------------------------------------------------------------------------
__global__ __launch_bounds__(256) void xpose_x(const float* __restrict__ x,
                                               unsigned short* __restrict__ xT) {
    const int b = blockIdx.y, h = blockIdx.x;
    __shared__ float tile[CIN * 129];                 // +1 pad: conflict-free
    const float* xp = x + (size_t)b * CIN * HW_ + (size_t)h * W_;
    for (int idx = threadIdx.x; idx < CIN * W_; idx += 256) {
        const int c = idx >> 7, w = idx & 127;
        tile[c * 129 + w] = xp[(size_t)c * HW_ + w];
    }
    __syncthreads();
    unsigned short* op = xT + ((size_t)b * H_ + h) * (W_ * CIN);
    for (int idx = threadIdx.x; idx < (W_ * CIN) / 8; idx += 256) {
        const int w = idx >> 3, c0 = (idx & 7) << 3;
        int4 v;
        v.x = f2bf(tile[(c0 + 0) * 129 + w]) | ((unsigned)f2bf(tile[(c0 + 1) * 129 + w]) << 16);
        v.y = f2bf(tile[(c0 + 2) * 129 + w]) | ((unsigned)f2bf(tile[(c0 + 3) * 129 + w]) << 16);
        v.z = f2bf(tile[(c0 + 4) * 129 + w]) | ((unsigned)f2bf(tile[(c0 + 5) * 129 + w]) << 16);
        v.w = f2bf(tile[(c0 + 6) * 129 + w]) | ((unsigned)f2bf(tile[(c0 + 7) * 129 + w]) << 16);
        *(int4*)(op + (w << 6) + c0) = v;
    }
}

// ---------------------------------------------------------------------------
// kernel fp32 [b][r][o][c][t] -> kT bf16 [b][r][t][o][c]
// LDS-staged transpose: coalesced float4 reads (old version: stride-36B scalar)
// block = (br, o-quarter): stages 16o x 64c x 9t contiguous floats
// ---------------------------------------------------------------------------
__global__ __launch_bounds__(256) void xpose_k(const float* __restrict__ kr,
                                               unsigned short* __restrict__ kT) {
    const int br = blockIdx.x >> 2, oq = blockIdx.x & 3;
    __shared__ float slab[16 * 64 * 9];               // 36 KB
    const float* src = kr + ((size_t)br * 64 + oq * 16) * (64 * 9);
    for (int idx = threadIdx.x; idx < 2304; idx += 256)
        *(float4*)&slab[idx << 2] = *(const float4*)&src[idx << 2];
    __syncthreads();
    unsigned short* dst = kT + (size_t)br * (9 * 4096) + oq * (16 * 64);
    for (int idx = threadIdx.x; idx < 1152; idx += 256) {
        const int t = idx >> 7, rem = idx & 127, o16 = rem >> 3, c8 = (rem & 7) << 3;
        unsigned short s[8];
        #pragma unroll
        for (int j = 0; j < 8; j++)
            s[j] = f2bf(slab[(o16 * 64 + c8 + j) * 9 + t]);
        int4 v;
        v.x = s[0] | ((unsigned)s[1] << 16);
        v.y = s[2] | ((unsigned)s[3] << 16);
        v.z = s[4] | ((unsigned)s[5] << 16);
        v.w = s[6] | ((unsigned)s[7] << 16);
        *(int4*)(dst + t * 4096 + o16 * 64 + c8) = v;
    }
}

// ---------------------------------------------------------------------------
// mask logits conv (fp32) + softmax over regions -> masks (= output #2)
// ---------------------------------------------------------------------------
__global__ __launch_bounds__(128) void mask_kernel(const float* __restrict__ x,
                                                   const float* __restrict__ mw,
                                                   const float* __restrict__ mb,
                                                   float* __restrict__ masks) {
    const int b = blockIdx.y, h = blockIdx.x, w = threadIdx.x;
    __shared__ float mws2[CIN * 3 * RN_ * 3];
    for (int i = threadIdx.x; i < CIN * 9 * RN_; i += 128) {
        const int r = i / 576, rem = i % 576, c = rem / 9, t = rem % 9;
        mws2[((c * 3 + t / 3) * 4 + r) * 3 + (t % 3)] = mw[i];
    }
    __syncthreads();
    float lg0 = mb[0], lg1 = mb[1], lg2 = mb[2], lg3 = mb[3];
    const float* xb = x + (size_t)b * CIN * HW_;
    #pragma unroll
    for (int dh = -1; dh <= 1; dh++) {
        const int hh = h + dh;
        if (hh < 0 || hh >= H_) continue;
        for (int c = 0; c < CIN; c++) {
            const float* row = xb + ((size_t)c * H_ + hh) * W_;
            const float xm1 = (w >= 1) ? row[w - 1] : 0.f;
            const float x0  = row[w];
            const float xp1 = (w < W_ - 1) ? row[w + 1] : 0.f;
            const float4* p = (const float4*)&mws2[(c * 3 + dh + 1) * 12];
            const float4 q0 = p[0], q1 = p[1], q2 = p[2];
            lg0 += q0.x * xm1 + q0.y * x0 + q0.z * xp1;
            lg1 += q0.w * xm1 + q1.x * x0 + q1.y * xp1;
            lg2 += q1.z * xm1 + q1.w * x0 + q2.x * xp1;
            lg3 += q2.y * xm1 + q2.z * x0 + q2.w * xp1;
        }
    }
    const float mx = fmaxf(fmaxf(lg0, lg1), fmaxf(lg2, lg3));
    const float e0 = __expf(lg0 - mx), e1 = __expf(lg1 - mx);
    const float e2 = __expf(lg2 - mx), e3 = __expf(lg3 - mx);
    const float inv = 1.f / (e0 + e1 + e2 + e3);
    float* mp = masks + (size_t)b * RN_ * HW_ + (size_t)h * W_ + w;
    mp[0] = e0 * inv; mp[HW_] = e1 * inv; mp[2 * HW_] = e2 * inv; mp[3 * HW_] = e3 * inv;
}

// ---------------------------------------------------------------------------
// fused dynamic grouped conv + mask-weighted region sum + BN + ReLU
// v2: A (kernel tile) goes global->VGPR double-buffered (no LDS, no K-loop
// barrier). LDS holds only the read-only x halo tile + masks + BN consts
// (40.6 KB -> 4 blocks/CU, whole grid co-resident, 8 waves/CU).
// ---------------------------------------------------------------------------
#define WPAD     72                      // 36 dw; 36==4 mod 32, 9==1 mod 8 -> 2-way only
#define XS_W     66                      // 64 + 2 halo columns
#define XS_ELEMS (4 * XS_W * WPAD)       // 19008 shorts = 38016 B

__global__ __launch_bounds__(128, 2) void main_conv(
        const unsigned short* __restrict__ xT,
        const unsigned short* __restrict__ kT,
        const float* __restrict__ masks,
        const float* __restrict__ bn_gamma, const float* __restrict__ bn_beta,
        const float* __restrict__ bn_mean,  const float* __restrict__ bn_var,
        float* __restrict__ outp) {
    __shared__ unsigned short xs[XS_ELEMS];
    __shared__ float masks_s[RN_ * 128];
    __shared__ float scale_s[COUT];
    __shared__ float shift_s[COUT];

    const int tid = threadIdx.x;
    const int b  = blockIdx.z;
    const int w0 = blockIdx.y << 6;           // 0 or 64
    const int h0 = blockIdx.x << 1;           // 0..126
    const int lane = tid & 63, wv = tid >> 6; // wave wv owns output row h0+wv
    const int i = lane & 15, g = lane >> 4;

    // ---- A prologue: rt=0 frags straight into VGPRs (issue before staging) ----
    // lane (i,g) of frag (fm,ks) = kT[b][rt][o=fm*16+i][c=ks*32+g*8 .. +8]
    const unsigned short* kb = kT + (size_t)b * (36 * 4096) + i * 64 + g * 8;
    v8s abuf[2][8];                           // [parity][fm*2+ks]
    #pragma unroll
    for (int f = 0; f < 8; f++)
        abuf[0][f] = *(const v8s*)(kb + ((f >> 1) << 10) + ((f & 1) << 5));

    // ---- stage x halo tile: rows h0-1..h0+2, cols w0-1..w0+64, 64 ch bf16 ----
    const unsigned short* xb = xT + (size_t)b * (HW_ * CIN);
    #pragma unroll
    for (int row = 0; row < 4; row++) {
        const int h_in = h0 - 1 + row;
        const bool hok = (h_in >= 0) && (h_in < H_);
        for (int idx = tid; idx < XS_W * 8; idx += 128) {
            const int w = idx >> 3, c8 = (idx & 7) << 3;
            const int w_in = w0 - 1 + w;
            int4 v = make_int4(0, 0, 0, 0);
            if (hok && (w_in >= 0) && (w_in < W_))
                v = *(const int4*)(xb + ((h_in * W_ + w_in) << 6) + c8);
            *(int4*)(&xs[(row * XS_W + w) * WPAD + c8]) = v;
        }
    }
    // ---- stage masks for this tile: [r][row*64+wl] ----
    #pragma unroll
    for (int q = 0; q < 4; q++) {
        const int idx = q * 128 + tid;
        const int r = idx >> 7, n = idx & 127;
        masks_s[idx] =
            masks[(((size_t)b * RN_ + r) * H_ + (h0 + (n >> 6))) * W_ + w0 + (n & 63)];
    }
    if (tid < COUT) {
        const float sc = bn_gamma[tid] * rsqrtf(bn_var[tid] + BN_EPS);
        scale_s[tid] = sc;
        shift_s[tid] = bn_beta[tid] - bn_mean[tid] * sc;
    }

    // per-lane B-fragment base addresses (tap center, ks=0)
    int bbase[4];
    #pragma unroll
    for (int fn = 0; fn < 4; fn++)
        bbase[fn] = ((wv + 1) * XS_W + fn * 16 + i + 1) * WPAD + g * 8;

    v4f y_acc[4][4], o_acc[4][4];
    #pragma unroll
    for (int fm = 0; fm < 4; fm++)
        #pragma unroll
        for (int fn = 0; fn < 4; fn++) {
            y_acc[fm][fn] = (v4f){0.f, 0.f, 0.f, 0.f};
            o_acc[fm][fn] = (v4f){0.f, 0.f, 0.f, 0.f};
        }

    __syncthreads();                          // the ONLY barrier

    #pragma unroll
    for (int rt = 0; rt < 36; rt++) {
        const int cur = rt & 1, nxt = cur ^ 1;
        if (rt < 35) {                        // prefetch next A tile into other buffer
            const unsigned short* kn = kb + ((rt + 1) << 12);
            #pragma unroll
            for (int f = 0; f < 8; f++)
                abuf[nxt][f] = *(const v8s*)(kn + ((f >> 1) << 10) + ((f & 1) << 5));
        }
        const int tap = rt % 9;
        const int toff = ((tap / 3) * XS_W + (tap % 3)) * WPAD - (XS_W + 1) * WPAD;
        #pragma unroll
        for (int ks = 0; ks < 2; ks++) {
            v8s bfr[4];
            #pragma unroll
            for (int fn = 0; fn < 4; fn++)
                bfr[fn] = *(const v8s*)(&xs[bbase[fn] + toff + ks * 32]);
            #pragma unroll
            for (int fm = 0; fm < 4; fm++)
                #pragma unroll
                for (int fn = 0; fn < 4; fn++)
                    y_acc[fm][fn] = __builtin_amdgcn_mfma_f32_16x16x32_bf16(
                        abuf[cur][fm * 2 + ks], bfr[fn], y_acc[fm][fn], 0, 0, 0);
        }
        if (tap == 8) {                       // region done: fold mask weight
            const int r = rt / 9;
            #pragma unroll
            for (int fn = 0; fn < 4; fn++) {
                const float mv = masks_s[r * 128 + wv * 64 + fn * 16 + i];
                #pragma unroll
                for (int fm = 0; fm < 4; fm++) {
                    o_acc[fm][fn] += mv * y_acc[fm][fn];
                    y_acc[fm][fn] = (v4f){0.f, 0.f, 0.f, 0.f};
                }
            }
        }
    }

    // ---- epilogue: BN + ReLU + store (C/D: n = i, m = g*4+reg within fm*16) ----
    const int h_out = h0 + wv;
    #pragma unroll
    for (int fm = 0; fm < 4; fm++) {
        #pragma unroll
        for (int reg = 0; reg < 4; reg++) {
            const int o = fm * 16 + g * 4 + reg;
            const float sc = scale_s[o], sh = shift_s[o];
            float* rowp = outp + (((size_t)b * COUT + o) * H_ + h_out) * W_ + w0 + i;
            #pragma unroll
            for (int fn = 0; fn < 4; fn++) {
                const float v = o_acc[fm][fn][reg] * sc + sh;
                rowp[fn * 16] = fmaxf(v, 0.f);
            }
        }
    }
}

// ---------------------------------------------------------------------------
extern "C" void kernel_launch(void* const* d_in, const int* in_sizes, int n_in,
                              void* d_out, int out_size, void* d_ws, size_t ws_size,
                              hipStream_t stream) {
    const float* x     = (const float*)d_in[0];
    const float* kr    = (const float*)d_in[1];
    const float* mw    = (const float*)d_in[2];
    const float* mb    = (const float*)d_in[3];
    const float* gamma = (const float*)d_in[4];
    const float* beta  = (const float*)d_in[5];
    const float* mean  = (const float*)d_in[6];
    const float* var   = (const float*)d_in[7];

    float* outp  = (float*)d_out;
    float* masks = outp + (size_t)B_ * COUT * HW_;          // output #2 region

    unsigned short* xT = (unsigned short*)d_ws;             // 16 MB
    unsigned short* kT = xT + (size_t)B_ * HW_ * CIN;       // +2.25 MB

    hipLaunchKernelGGL(xpose_x, dim3(H_, B_), dim3(256), 0, stream, x, xT);
    hipLaunchKernelGGL(xpose_k, dim3(128), dim3(256), 0, stream, kr, kT);
    hipLaunchKernelGGL(mask_kernel, dim3(H_, B_), dim3(128), 0, stream, x, mw, mb, masks);
    hipLaunchKernelGGL(main_conv, dim3(H_ / 2, 2, B_), dim3(128), 0, stream,
                       xT, kT, masks, gamma, beta, mean, var, outp);
}

// Round 4
// 196.725 us; speedup vs baseline: 1.8909x; 1.8909x over previous
//
#include <hip/hip_runtime.h>
#include <hip/hip_bf16.h>

#define B_    8
#define CIN   64
#define COUT  64
#define RN_   4
#define H_    128
#define W_    128
#define HW_   (H_ * W_)
#define BN_EPS 1e-5f

typedef short v8s __attribute__((ext_vector_type(8)));
typedef float v4f __attribute__((ext_vector_type(4)));

__device__ __forceinline__ unsigned short f2bf(float f) {
    unsigned int u = __float_as_uint(f);
    u += 0x7FFFu + ((u >> 16) & 1u);       // round-to-nearest-even
    return (unsigned short)(u >> 16);
}

// ---------------------------------------------------------------------------
// x fp32 [b][c][h][w] -> xT bf16 [b][h][w][c]   (channel-innermost for b128 LDS)
// ---------------------------------------------------------------------------
__global__ __launch_bounds__(256) void xpose_x(const float* __restrict__ x,
                                               unsigned short* __restrict__ xT) {
    const int b = blockIdx.y, h = blockIdx.x;
    __shared__ float tile[CIN * 129];                 // +1 pad: conflict-free
    const float* xp = x + (size_t)b * CIN * HW_ + (size_t)h * W_;
    for (int idx = threadIdx.x; idx < CIN * W_; idx += 256) {
        const int c = idx >> 7, w = idx & 127;
        tile[c * 129 + w] = xp[(size_t)c * HW_ + w];
    }
    __syncthreads();
    unsigned short* op = xT + ((size_t)b * H_ + h) * (W_ * CIN);
    for (int idx = threadIdx.x; idx < (W_ * CIN) / 8; idx += 256) {
        const int w = idx >> 3, c0 = (idx & 7) << 3;
        int4 v;
        v.x = f2bf(tile[(c0 + 0) * 129 + w]) | ((unsigned)f2bf(tile[(c0 + 1) * 129 + w]) << 16);
        v.y = f2bf(tile[(c0 + 2) * 129 + w]) | ((unsigned)f2bf(tile[(c0 + 3) * 129 + w]) << 16);
        v.z = f2bf(tile[(c0 + 4) * 129 + w]) | ((unsigned)f2bf(tile[(c0 + 5) * 129 + w]) << 16);
        v.w = f2bf(tile[(c0 + 6) * 129 + w]) | ((unsigned)f2bf(tile[(c0 + 7) * 129 + w]) << 16);
        *(int4*)(op + (w << 6) + c0) = v;
    }
}

// ---------------------------------------------------------------------------
// kernel fp32 [b][r][o][c][t] -> kT bf16 [b][r][t][o][c]
// LDS-staged transpose: coalesced float4 reads
// ---------------------------------------------------------------------------
__global__ __launch_bounds__(256) void xpose_k(const float* __restrict__ kr,
                                               unsigned short* __restrict__ kT) {
    const int br = blockIdx.x >> 2, oq = blockIdx.x & 3;
    __shared__ float slab[16 * 64 * 9];               // 36 KB
    const float* src = kr + ((size_t)br * 64 + oq * 16) * (64 * 9);
    for (int idx = threadIdx.x; idx < 2304; idx += 256)
        *(float4*)&slab[idx << 2] = *(const float4*)&src[idx << 2];
    __syncthreads();
    unsigned short* dst = kT + (size_t)br * (9 * 4096) + oq * (16 * 64);
    for (int idx = threadIdx.x; idx < 1152; idx += 256) {
        const int t = idx >> 7, rem = idx & 127, o16 = rem >> 3, c8 = (rem & 7) << 3;
        unsigned short s[8];
        #pragma unroll
        for (int j = 0; j < 8; j++)
            s[j] = f2bf(slab[(o16 * 64 + c8 + j) * 9 + t]);
        int4 v;
        v.x = s[0] | ((unsigned)s[1] << 16);
        v.y = s[2] | ((unsigned)s[3] << 16);
        v.z = s[4] | ((unsigned)s[5] << 16);
        v.w = s[6] | ((unsigned)s[7] << 16);
        *(int4*)(dst + t * 4096 + o16 * 64 + c8) = v;
    }
}

// ---------------------------------------------------------------------------
// mask logits conv (fp32) + softmax over regions -> masks (= output #2)
// ---------------------------------------------------------------------------
__global__ __launch_bounds__(128) void mask_kernel(const float* __restrict__ x,
                                                   const float* __restrict__ mw,
                                                   const float* __restrict__ mb,
                                                   float* __restrict__ masks) {
    const int b = blockIdx.y, h = blockIdx.x, w = threadIdx.x;
    __shared__ float mws2[CIN * 3 * RN_ * 3];
    for (int i = threadIdx.x; i < CIN * 9 * RN_; i += 128) {
        const int r = i / 576, rem = i % 576, c = rem / 9, t = rem % 9;
        mws2[((c * 3 + t / 3) * 4 + r) * 3 + (t % 3)] = mw[i];
    }
    __syncthreads();
    float lg0 = mb[0], lg1 = mb[1], lg2 = mb[2], lg3 = mb[3];
    const float* xb = x + (size_t)b * CIN * HW_;
    #pragma unroll
    for (int dh = -1; dh <= 1; dh++) {
        const int hh = h + dh;
        if (hh < 0 || hh >= H_) continue;
        for (int c = 0; c < CIN; c++) {
            const float* row = xb + ((size_t)c * H_ + hh) * W_;
            const float xm1 = (w >= 1) ? row[w - 1] : 0.f;
            const float x0  = row[w];
            const float xp1 = (w < W_ - 1) ? row[w + 1] : 0.f;
            const float4* p = (const float4*)&mws2[(c * 3 + dh + 1) * 12];
            const float4 q0 = p[0], q1 = p[1], q2 = p[2];
            lg0 += q0.x * xm1 + q0.y * x0 + q0.z * xp1;
            lg1 += q0.w * xm1 + q1.x * x0 + q1.y * xp1;
            lg2 += q1.z * xm1 + q1.w * x0 + q2.x * xp1;
            lg3 += q2.y * xm1 + q2.z * x0 + q2.w * xp1;
        }
    }
    const float mx = fmaxf(fmaxf(lg0, lg1), fmaxf(lg2, lg3));
    const float e0 = __expf(lg0 - mx), e1 = __expf(lg1 - mx);
    const float e2 = __expf(lg2 - mx), e3 = __expf(lg3 - mx);
    const float inv = 1.f / (e0 + e1 + e2 + e3);
    float* mp = masks + (size_t)b * RN_ * HW_ + (size_t)h * W_ + w;
    mp[0] = e0 * inv; mp[HW_] = e1 * inv; mp[2 * HW_] = e2 * inv; mp[3 * HW_] = e3 * inv;
}

// ---------------------------------------------------------------------------
// fused dynamic grouped conv + mask-weighted region sum + BN + ReLU
// v3: 256 threads = 4 waves, 4 output rows/block (one per wave).
// A tile double-buffered via LDS (round-2 proven path, no spill);
// LDS 80 KB -> 2 blocks/CU = 8 waves/CU = 2 waves/SIMD; 1 barrier per rt.
// ---------------------------------------------------------------------------
#define WPAD     72                      // 36 dw; 36==4 mod 32 -> benign 2-way
#define XS_W     66                      // 64 + 2 halo columns
#define XS_ROWS  6                       // 4 output rows + 2 halo rows
#define AS_ELEMS (COUT * WPAD)           // 4608 shorts per buffer
#define XS_ELEMS (XS_ROWS * XS_W * WPAD) // 28512 shorts = 57 KB

__global__ __launch_bounds__(256, 2) void main_conv(
        const unsigned short* __restrict__ xT,
        const unsigned short* __restrict__ kT,
        const float* __restrict__ masks,
        const float* __restrict__ bn_gamma, const float* __restrict__ bn_beta,
        const float* __restrict__ bn_mean,  const float* __restrict__ bn_var,
        float* __restrict__ outp) {
    __shared__ unsigned short xs[XS_ELEMS];
    __shared__ unsigned short as[2 * AS_ELEMS];
    __shared__ float masks_s[RN_ * 256];
    __shared__ float scale_s[COUT];
    __shared__ float shift_s[COUT];

    const int tid = threadIdx.x;
    const int b  = blockIdx.z;
    const int w0 = blockIdx.y << 6;           // 0 or 64
    const int h0 = blockIdx.x << 2;           // 0..124
    const int lane = tid & 63, wv = tid >> 6; // wave wv owns output row h0+wv
    const int i = lane & 15, g = lane >> 4;

    // ---- A prologue: rt=0 tile (4096 shorts = 512 x int4), 2 int4/thread ----
    const unsigned short* kb = kT + (size_t)b * (36 * 4096);
    int4 areg[2];
    #pragma unroll
    for (int q = 0; q < 2; q++)
        areg[q] = *(const int4*)(kb + ((q * 256 + tid) << 3));

    // ---- stage x halo tile: rows h0-1..h0+4, cols w0-1..w0+64, 64 ch bf16 ----
    const unsigned short* xb = xT + (size_t)b * (HW_ * CIN);
    #pragma unroll
    for (int row = 0; row < XS_ROWS; row++) {
        const int h_in = h0 - 1 + row;
        const bool hok = (h_in >= 0) && (h_in < H_);
        for (int idx = tid; idx < XS_W * 8; idx += 256) {
            const int w = idx >> 3, c8 = (idx & 7) << 3;
            const int w_in = w0 - 1 + w;
            int4 v = make_int4(0, 0, 0, 0);
            if (hok && (w_in >= 0) && (w_in < W_))
                v = *(const int4*)(xb + ((h_in * W_ + w_in) << 6) + c8);
            *(int4*)(&xs[(row * XS_W + w) * WPAD + c8]) = v;
        }
    }
    // ---- stage masks for this tile: [r][row*64 + w] ----
    #pragma unroll
    for (int q = 0; q < 4; q++) {
        const int idx = q * 256 + tid;
        const int r = idx >> 8, n = idx & 255;
        masks_s[idx] =
            masks[(((size_t)b * RN_ + r) * H_ + (h0 + (n >> 6))) * W_ + w0 + (n & 63)];
    }
    if (tid < COUT) {
        const float sc = bn_gamma[tid] * rsqrtf(bn_var[tid] + BN_EPS);
        scale_s[tid] = sc;
        shift_s[tid] = bn_beta[tid] - bn_mean[tid] * sc;
    }

    // per-lane B-fragment base addresses (tap center, ks=0)
    int bbase[4];
    #pragma unroll
    for (int fn = 0; fn < 4; fn++)
        bbase[fn] = ((wv + 1) * XS_W + fn * 16 + i + 1) * WPAD + g * 8;

    v4f y_acc[4][4], o_acc[4][4];
    #pragma unroll
    for (int fm = 0; fm < 4; fm++)
        #pragma unroll
        for (int fn = 0; fn < 4; fn++) {
            y_acc[fm][fn] = (v4f){0.f, 0.f, 0.f, 0.f};
            o_acc[fm][fn] = (v4f){0.f, 0.f, 0.f, 0.f};
        }

    int r = 0, tap = 0;
    for (int rt = 0; rt < 36; rt++) {
        const int buf = (rt & 1) * AS_ELEMS;
        // regs -> LDS A buffer: chunk c = q*256+tid covers o = c>>3, ch (c&7)*8
        #pragma unroll
        for (int q = 0; q < 2; q++) {
            const int c = q * 256 + tid;
            *(int4*)(&as[buf + (c >> 3) * WPAD + ((c & 7) << 3)]) = areg[q];
        }
        __syncthreads();                      // single barrier per rt (dbuf-safe)
        if (rt < 35) {                        // prefetch next A tile
            const unsigned short* kn = kb + ((rt + 1) << 12);
            #pragma unroll
            for (int q = 0; q < 2; q++)
                areg[q] = *(const int4*)(kn + ((q * 256 + tid) << 3));
        }
        const int toff = ((tap / 3) * XS_W + (tap % 3)) * WPAD - (XS_W + 1) * WPAD;
        #pragma unroll
        for (int ks = 0; ks < 2; ks++) {
            v8s a[4], bfr[4];
            #pragma unroll
            for (int fm = 0; fm < 4; fm++)
                a[fm] = *(const v8s*)(&as[buf + (fm * 16 + i) * WPAD + ks * 32 + g * 8]);
            #pragma unroll
            for (int fn = 0; fn < 4; fn++)
                bfr[fn] = *(const v8s*)(&xs[bbase[fn] + toff + ks * 32]);
            #pragma unroll
            for (int fm = 0; fm < 4; fm++)
                #pragma unroll
                for (int fn = 0; fn < 4; fn++)
                    y_acc[fm][fn] = __builtin_amdgcn_mfma_f32_16x16x32_bf16(
                        a[fm], bfr[fn], y_acc[fm][fn], 0, 0, 0);
        }
        if (++tap == 9) {                     // region done: fold mask weight
            tap = 0;
            #pragma unroll
            for (int fn = 0; fn < 4; fn++) {
                const float mv = masks_s[r * 256 + wv * 64 + fn * 16 + i];
                #pragma unroll
                for (int fm = 0; fm < 4; fm++) {
                    o_acc[fm][fn] += mv * y_acc[fm][fn];
                    y_acc[fm][fn] = (v4f){0.f, 0.f, 0.f, 0.f};
                }
            }
            r++;
        }
    }

    // ---- epilogue: BN + ReLU + store (C/D: n = i, m = g*4+reg within fm*16) ----
    const int h_out = h0 + wv;
    #pragma unroll
    for (int fm = 0; fm < 4; fm++) {
        #pragma unroll
        for (int reg = 0; reg < 4; reg++) {
            const int o = fm * 16 + g * 4 + reg;
            const float sc = scale_s[o], sh = shift_s[o];
            float* rowp = outp + (((size_t)b * COUT + o) * H_ + h_out) * W_ + w0 + i;
            #pragma unroll
            for (int fn = 0; fn < 4; fn++) {
                const float v = o_acc[fm][fn][reg] * sc + sh;
                rowp[fn * 16] = fmaxf(v, 0.f);
            }
        }
    }
}

// ---------------------------------------------------------------------------
extern "C" void kernel_launch(void* const* d_in, const int* in_sizes, int n_in,
                              void* d_out, int out_size, void* d_ws, size_t ws_size,
                              hipStream_t stream) {
    const float* x     = (const float*)d_in[0];
    const float* kr    = (const float*)d_in[1];
    const float* mw    = (const float*)d_in[2];
    const float* mb    = (const float*)d_in[3];
    const float* gamma = (const float*)d_in[4];
    const float* beta  = (const float*)d_in[5];
    const float* mean  = (const float*)d_in[6];
    const float* var   = (const float*)d_in[7];

    float* outp  = (float*)d_out;
    float* masks = outp + (size_t)B_ * COUT * HW_;          // output #2 region

    unsigned short* xT = (unsigned short*)d_ws;             // 16 MB
    unsigned short* kT = xT + (size_t)B_ * HW_ * CIN;       // +2.25 MB

    hipLaunchKernelGGL(xpose_x, dim3(H_, B_), dim3(256), 0, stream, x, xT);
    hipLaunchKernelGGL(xpose_k, dim3(128), dim3(256), 0, stream, kr, kT);
    hipLaunchKernelGGL(mask_kernel, dim3(H_, B_), dim3(128), 0, stream, x, mw, mb, masks);
    hipLaunchKernelGGL(main_conv, dim3(H_ / 4, 2, B_), dim3(256), 0, stream,
                       xT, kT, masks, gamma, beta, mean, var, outp);
}

// Round 5
// 156.469 us; speedup vs baseline: 2.3774x; 1.2573x over previous
//
#include <hip/hip_runtime.h>
#include <hip/hip_bf16.h>

#define B_    8
#define CIN   64
#define COUT  64
#define RN_   4
#define H_    128
#define W_    128
#define HW_   (H_ * W_)
#define BN_EPS 1e-5f

typedef short v8s __attribute__((ext_vector_type(8)));
typedef float v4f __attribute__((ext_vector_type(4)));

__device__ __forceinline__ unsigned short f2bf(float f) {
    unsigned int u = __float_as_uint(f);
    u += 0x7FFFu + ((u >> 16) & 1u);       // round-to-nearest-even
    return (unsigned short)(u >> 16);
}

// ---------------------------------------------------------------------------
// prep: merged transpose kernels (one launch)
//   blocks [0,1024):   x fp32 [b][c][h][w] -> xT bf16 [b][h][w][c]
//   blocks [1024,1152): kernel fp32 [b][r][o][c][t] -> kT bf16 [b][r][t][o][c]
// ---------------------------------------------------------------------------
__global__ __launch_bounds__(256) void prep(const float* __restrict__ x,
                                            const float* __restrict__ kr,
                                            unsigned short* __restrict__ xT,
                                            unsigned short* __restrict__ kT) {
    __shared__ float sl[16 * 64 * 9];                 // 36 KB (union of both uses)
    if (blockIdx.x < 1024) {
        const int b = blockIdx.x >> 7, h = blockIdx.x & 127;
        const float* xp = x + (size_t)b * CIN * HW_ + (size_t)h * W_;
        for (int idx = threadIdx.x; idx < CIN * W_; idx += 256) {
            const int c = idx >> 7, w = idx & 127;
            sl[c * 129 + w] = xp[(size_t)c * HW_ + w];
        }
        __syncthreads();
        unsigned short* op = xT + ((size_t)b * H_ + h) * (W_ * CIN);
        for (int idx = threadIdx.x; idx < (W_ * CIN) / 8; idx += 256) {
            const int w = idx >> 3, c0 = (idx & 7) << 3;
            int4 v;
            v.x = f2bf(sl[(c0 + 0) * 129 + w]) | ((unsigned)f2bf(sl[(c0 + 1) * 129 + w]) << 16);
            v.y = f2bf(sl[(c0 + 2) * 129 + w]) | ((unsigned)f2bf(sl[(c0 + 3) * 129 + w]) << 16);
            v.z = f2bf(sl[(c0 + 4) * 129 + w]) | ((unsigned)f2bf(sl[(c0 + 5) * 129 + w]) << 16);
            v.w = f2bf(sl[(c0 + 6) * 129 + w]) | ((unsigned)f2bf(sl[(c0 + 7) * 129 + w]) << 16);
            *(int4*)(op + (w << 6) + c0) = v;
        }
    } else {
        const int bid = blockIdx.x - 1024;
        const int br = bid >> 2, oq = bid & 3;
        const float* src = kr + ((size_t)br * 64 + oq * 16) * (64 * 9);
        for (int idx = threadIdx.x; idx < 2304; idx += 256)
            *(float4*)&sl[idx << 2] = *(const float4*)&src[idx << 2];
        __syncthreads();
        unsigned short* dst = kT + (size_t)br * (9 * 4096) + oq * (16 * 64);
        for (int idx = threadIdx.x; idx < 1152; idx += 256) {
            const int t = idx >> 7, rem = idx & 127, o16 = rem >> 3, c8 = (rem & 7) << 3;
            unsigned short s[8];
            #pragma unroll
            for (int j = 0; j < 8; j++)
                s[j] = f2bf(sl[(o16 * 64 + c8 + j) * 9 + t]);
            int4 v;
            v.x = s[0] | ((unsigned)s[1] << 16);
            v.y = s[2] | ((unsigned)s[3] << 16);
            v.z = s[4] | ((unsigned)s[5] << 16);
            v.w = s[6] | ((unsigned)s[7] << 16);
            *(int4*)(dst + t * 4096 + o16 * 64 + c8) = v;
        }
    }
}

// ---------------------------------------------------------------------------
// fused: dynamic grouped conv + mask conv/softmax (MFMA, fused) + region sum
// + BN + ReLU.  256 threads = 4 waves, 4 output rows/block.
// Mask logits ride the region-0 pass: same B-frags, tiny A (mask weights).
// Masks broadcast lane->lane via __shfl (no LDS/global round-trip).
// ---------------------------------------------------------------------------
#define WPAD     72                      // 36 dw; benign 2-way spread
#define XS_W     66                      // 64 + 2 halo columns
#define XS_ROWS  6                       // 4 output rows + 2 halo rows
#define AS_ELEMS (COUT * WPAD)           // 4608 shorts per buffer
#define XS_ELEMS (XS_ROWS * XS_W * WPAD) // 28512 shorts = 57 KB

__global__ __launch_bounds__(256, 2) void main_conv(
        const unsigned short* __restrict__ xT,
        const unsigned short* __restrict__ kT,
        const float* __restrict__ mw, const float* __restrict__ mb,
        const float* __restrict__ bn_gamma, const float* __restrict__ bn_beta,
        const float* __restrict__ bn_mean,  const float* __restrict__ bn_var,
        float* __restrict__ outp, float* __restrict__ masks_g) {
    __shared__ unsigned short xs[XS_ELEMS];
    __shared__ unsigned short as[2 * AS_ELEMS];
    __shared__ unsigned short mws[9 * 4 * 64];        // [tap][r][c] bf16, 4.5 KB
    __shared__ float scale_s[COUT];
    __shared__ float shift_s[COUT];

    const int tid = threadIdx.x;
    const int b  = blockIdx.z;
    const int w0 = blockIdx.y << 6;           // 0 or 64
    const int h0 = blockIdx.x << 2;           // 0..124
    const int lane = tid & 63, wv = tid >> 6; // wave wv owns output row h0+wv
    const int i = lane & 15, g = lane >> 4;
    const int h_out = h0 + wv;

    // ---- A prologue: rt=0 tile (4096 shorts = 512 x int4), 2 int4/thread ----
    const unsigned short* kb = kT + (size_t)b * (36 * 4096);
    int4 areg[2];
    #pragma unroll
    for (int q = 0; q < 2; q++)
        areg[q] = *(const int4*)(kb + ((q * 256 + tid) << 3));

    // ---- stage x halo tile: rows h0-1..h0+4, cols w0-1..w0+64, 64 ch bf16 ----
    const unsigned short* xb = xT + (size_t)b * (HW_ * CIN);
    #pragma unroll
    for (int row = 0; row < XS_ROWS; row++) {
        const int h_in = h0 - 1 + row;
        const bool hok = (h_in >= 0) && (h_in < H_);
        for (int idx = tid; idx < XS_W * 8; idx += 256) {
            const int w = idx >> 3, c8 = (idx & 7) << 3;
            const int w_in = w0 - 1 + w;
            int4 v = make_int4(0, 0, 0, 0);
            if (hok && (w_in >= 0) && (w_in < W_))
                v = *(const int4*)(xb + ((h_in * W_ + w_in) << 6) + c8);
            *(int4*)(&xs[(row * XS_W + w) * WPAD + c8]) = v;
        }
    }
    // ---- stage mask weights: mws[tap][r][c] = bf16(mw[r][c][tap]) ----
    for (int idx = tid; idx < 9 * 4 * 64; idx += 256) {
        const int t = idx >> 8, rc = idx & 255, r = rc >> 6, c = rc & 63;
        mws[(t << 8) + (r << 6) + c] = f2bf(mw[((r << 6) + c) * 9 + t]);
    }
    if (tid < COUT) {
        const float sc = bn_gamma[tid] * rsqrtf(bn_var[tid] + BN_EPS);
        scale_s[tid] = sc;
        shift_s[tid] = bn_beta[tid] - bn_mean[tid] * sc;
    }
    const float mb0 = mb[0], mb1 = mb[1], mb2 = mb[2], mb3 = mb[3];

    // per-lane B-fragment base addresses (tap center, ks=0)
    int bbase[4];
    #pragma unroll
    for (int fn = 0; fn < 4; fn++)
        bbase[fn] = ((wv + 1) * XS_W + fn * 16 + i + 1) * WPAD + g * 8;

    v4f y_acc[4][4], o_acc[4][4], lg_acc[4];
    #pragma unroll
    for (int fm = 0; fm < 4; fm++)
        #pragma unroll
        for (int fn = 0; fn < 4; fn++) {
            y_acc[fm][fn] = (v4f){0.f, 0.f, 0.f, 0.f};
            o_acc[fm][fn] = (v4f){0.f, 0.f, 0.f, 0.f};
        }
    #pragma unroll
    for (int fn = 0; fn < 4; fn++) lg_acc[fn] = (v4f){0.f, 0.f, 0.f, 0.f};

    unsigned mk0[4], mk1[4];                  // bf16-packed masks: [fn] (r0|r1), (r2|r3)

    int r = 0, tap = 0;
    for (int rt = 0; rt < 36; rt++) {
        const int buf = (rt & 1) * AS_ELEMS;
        #pragma unroll
        for (int q = 0; q < 2; q++) {
            const int c = q * 256 + tid;
            *(int4*)(&as[buf + (c >> 3) * WPAD + ((c & 7) << 3)]) = areg[q];
        }
        __syncthreads();                      // single barrier per rt (dbuf-safe)
        if (rt < 35) {
            const unsigned short* kn = kb + ((rt + 1) << 12);
            #pragma unroll
            for (int q = 0; q < 2; q++)
                areg[q] = *(const int4*)(kn + ((q * 256 + tid) << 3));
        }
        const int toff = ((tap / 3) * XS_W + (tap % 3)) * WPAD - (XS_W + 1) * WPAD;
        const bool do_lg = (rt < 9);          // region-0 pass also feeds logits
        #pragma unroll
        for (int ks = 0; ks < 2; ks++) {
            v8s a[4], bfr[4];
            #pragma unroll
            for (int fm = 0; fm < 4; fm++)
                a[fm] = *(const v8s*)(&as[buf + (fm * 16 + i) * WPAD + ks * 32 + g * 8]);
            #pragma unroll
            for (int fn = 0; fn < 4; fn++)
                bfr[fn] = *(const v8s*)(&xs[bbase[fn] + toff + ks * 32]);
            if (do_lg) {
                const v8s am = *(const v8s*)(&mws[(tap << 8) + ((i & 3) << 6) + ks * 32 + g * 8]);
                #pragma unroll
                for (int fn = 0; fn < 4; fn++)
                    lg_acc[fn] = __builtin_amdgcn_mfma_f32_16x16x32_bf16(
                        am, bfr[fn], lg_acc[fn], 0, 0, 0);
            }
            #pragma unroll
            for (int fm = 0; fm < 4; fm++)
                #pragma unroll
                for (int fn = 0; fn < 4; fn++)
                    y_acc[fm][fn] = __builtin_amdgcn_mfma_f32_16x16x32_bf16(
                        a[fm], bfr[fn], y_acc[fm][fn], 0, 0, 0);
        }
        if (rt == 8) {                        // logits complete: softmax + emit masks
            #pragma unroll
            for (int fn = 0; fn < 4; fn++) {
                const float l0 = lg_acc[fn][0] + mb0, l1 = lg_acc[fn][1] + mb1;
                const float l2 = lg_acc[fn][2] + mb2, l3 = lg_acc[fn][3] + mb3;
                const float mx = fmaxf(fmaxf(l0, l1), fmaxf(l2, l3));
                const float e0 = __expf(l0 - mx), e1 = __expf(l1 - mx);
                const float e2 = __expf(l2 - mx), e3 = __expf(l3 - mx);
                const float inv = 1.f / (e0 + e1 + e2 + e3);
                const float m0 = e0 * inv, m1 = e1 * inv, m2 = e2 * inv, m3 = e3 * inv;
                if (g == 0) {                 // lanes 0..15 hold valid rows 0..3
                    float* mp = masks_g + ((size_t)b * RN_ * H_ + h_out) * W_ + w0 + fn * 16 + i;
                    mp[0] = m0; mp[HW_] = m1; mp[2 * HW_] = m2; mp[3 * HW_] = m3;
                }
                mk0[fn] = f2bf(m0) | ((unsigned)f2bf(m1) << 16);
                mk1[fn] = f2bf(m2) | ((unsigned)f2bf(m3) << 16);
            }
        }
        if (++tap == 9) {                     // region done: fold mask weight
            tap = 0;
            #pragma unroll
            for (int fn = 0; fn < 4; fn++) {
                unsigned pk = (r & 2) ? mk1[fn] : mk0[fn];
                pk = __shfl(pk, i);           // broadcast from g==0 lane of col i
                const float mv = (r & 1) ? __uint_as_float(pk & 0xffff0000u)
                                         : __uint_as_float(pk << 16);
                #pragma unroll
                for (int fm = 0; fm < 4; fm++) {
                    o_acc[fm][fn] += mv * y_acc[fm][fn];
                    y_acc[fm][fn] = (v4f){0.f, 0.f, 0.f, 0.f};
                }
            }
            r++;
        }
    }

    // ---- epilogue: BN + ReLU + store (C/D: n = i, m = g*4+reg within fm*16) ----
    #pragma unroll
    for (int fm = 0; fm < 4; fm++) {
        #pragma unroll
        for (int reg = 0; reg < 4; reg++) {
            const int o = fm * 16 + g * 4 + reg;
            const float sc = scale_s[o], sh = shift_s[o];
            float* rowp = outp + (((size_t)b * COUT + o) * H_ + h_out) * W_ + w0 + i;
            #pragma unroll
            for (int fn = 0; fn < 4; fn++) {
                const float v = o_acc[fm][fn][reg] * sc + sh;
                rowp[fn * 16] = fmaxf(v, 0.f);
            }
        }
    }
}

// ---------------------------------------------------------------------------
extern "C" void kernel_launch(void* const* d_in, const int* in_sizes, int n_in,
                              void* d_out, int out_size, void* d_ws, size_t ws_size,
                              hipStream_t stream) {
    const float* x     = (const float*)d_in[0];
    const float* kr    = (const float*)d_in[1];
    const float* mw    = (const float*)d_in[2];
    const float* mb    = (const float*)d_in[3];
    const float* gamma = (const float*)d_in[4];
    const float* beta  = (const float*)d_in[5];
    const float* mean  = (const float*)d_in[6];
    const float* var   = (const float*)d_in[7];

    float* outp  = (float*)d_out;
    float* masks = outp + (size_t)B_ * COUT * HW_;          // output #2 region

    unsigned short* xT = (unsigned short*)d_ws;             // 16 MB
    unsigned short* kT = xT + (size_t)B_ * HW_ * CIN;       // +2.25 MB

    hipLaunchKernelGGL(prep, dim3(1152), dim3(256), 0, stream, x, kr, xT, kT);
    hipLaunchKernelGGL(main_conv, dim3(H_ / 4, 2, B_), dim3(256), 0, stream,
                       xT, kT, mw, mb, gamma, beta, mean, var, outp, masks);
}